// Round 5
// baseline (205.488 us; speedup 1.0000x reference)
//
#include <hip/hip_runtime.h>
#include <hip/hip_cooperative_groups.h>

namespace cg = cooperative_groups;

// PhraseAveragePretrainedEmbedding — prefix-sum formulation, v5.
// out[b,t,:] = (P[e]-P[a]) / max(e-a,1); spans contiguous by the XOR-mask
// identity (a=min(lo,hi+1), e=max(lo,hi+1)).
//
// v4 post-mortem: all top-5 dispatches are harness ws-poison fills (~44 µs,
// 268 MB each); our 4 kernels sum to ~43 µs. csum+buildP gathered W twice
// and used a kernel boundary purely as a barrier.
// v5: single cooperative kernel with one grid.sync — W gathered ONCE into
// LDS (38.4 KB/block, 512 blocks = 2/CU co-resident, 10 waves/CU), chunk
// sums published with plain stores (no sc1 atomics, unlike R3).
//
//   1. leaves_kernel: ballot compaction, loads hoisted to registers
//   2. fusedP (cooperative): gather->LDS + csum | grid.sync | prefix + P
//   3. out_kernel: out = (P[e]-P[a]) * inv, float4 (300 = 75*4)

#define BB 8
#define TT 4095
#define SS 2048
#define DD 300
#define PADIDX 1
#define CHUNK 32
#define NC (SS / CHUNK)  // 64
#define NTB 320

__global__ __launch_bounds__(512) void leaves_kernel(const int* __restrict__ x,
                                                     const int* __restrict__ idx,
                                                     int* __restrict__ leaves) {
    int b = blockIdx.x, tid = threadIdx.x;
    int lane = tid & 63, w = tid >> 6;  // 8 waves
    __shared__ int wcnt[8];
    __shared__ int sbase;
    if (tid == 0) sbase = 0;
    const int* xb = x + b * TT;
    const int* ib = idx + b * 2 * TT;

    // hoist all loads: segment k covers t in [k*512, (k+1)*512)
    int xv[8];
    bool lf8[8];
#pragma unroll
    for (int k = 0; k < 8; ++k) {
        int t = tid + k * 512;
        xv[k] = 0;
        lf8[k] = false;
        if (t < TT) {
            xv[k] = xb[t];
            lf8[k] = (ib[2 * t] == ib[2 * t + 1]) && (xv[k] != PADIDX);
        }
    }
    __syncthreads();
#pragma unroll
    for (int k = 0; k < 8; ++k) {
        unsigned long long bal = __ballot(lf8[k]);
        if (lane == 0) wcnt[w] = __popcll(bal);
        __syncthreads();
        int off = sbase;
        for (int i = 0; i < w; ++i) off += wcnt[i];
        int pos = off + __popcll(bal & ((1ull << lane) - 1ull));
        if (lf8[k] && pos < SS) leaves[b * SS + pos] = xv[k];
        __syncthreads();
        if (tid == 0) {
            int s = 0;
            for (int i = 0; i < 8; ++i) s += wcnt[i];
            sbase += s;
        }
        __syncthreads();
    }
    for (int i = sbase + tid; i < SS; i += 512) leaves[b * SS + i] = PADIDX;
}

__global__ __launch_bounds__(NTB, 2) void fusedP_kernel(const int* __restrict__ leaves,
                                                        const float* __restrict__ W,
                                                        float* __restrict__ csum,
                                                        float* __restrict__ P) {
    int blk = blockIdx.x;
    int b = blk >> 6, c = blk & (NC - 1);
    int tid = threadIdx.x;

    __shared__ int lf[CHUNK];
    __shared__ float sw[CHUNK * DD];  // 38400 B -> 2 blocks/CU

    if (tid < CHUNK) lf[tid] = leaves[b * SS + c * CHUNK + tid];
    __syncthreads();

    int d = tid;
    if (d < DD) {
        float agg = 0.f;
#pragma unroll 8
        for (int i = 0; i < CHUNK; ++i) {
            float v = W[lf[i] * DD + d];
            sw[i * DD + d] = v;
            agg += v;
        }
        csum[(b * NC + c) * DD + d] = agg;
    }
    __syncthreads();
    __threadfence();          // make csum visible device-wide (cross-XCD)
    cg::this_grid().sync();   // one global barrier (all 512 blocks co-resident)

    if (d < DD) {
        float run = 0.f;
#pragma unroll 4
        for (int cc = 0; cc < c; ++cc) run += csum[(b * NC + cc) * DD + d];

        float* Pb = P + (size_t)b * (SS + 1) * DD;
        int s0 = c * CHUNK;
#pragma unroll 4
        for (int i = 0; i < CHUNK; ++i) {
            Pb[(s0 + i) * DD + d] = run;
            run += sw[i * DD + d];
        }
        if (c == NC - 1) Pb[SS * DD + d] = run;
    }
}

// 320 threads = 4 row-groups x 80 lanes (75 active float4 lanes); 16 rows/block
__global__ __launch_bounds__(NTB) void out_kernel(const int* __restrict__ idx,
                                                  const float* __restrict__ P,
                                                  float* __restrict__ out) {
    int tid = threadIdx.x;
    int r = tid / 80, j = tid - r * 80;
    int base_bt = blockIdx.x * 16 + r;
    const float4* P4 = (const float4*)P;
    float4* out4 = (float4*)out;
#pragma unroll
    for (int it = 0; it < 4; ++it) {
        int bt = base_bt + it * 4;
        if (bt >= BB * TT || j >= 75) continue;
        int b = bt / TT;
        int lo = idx[2 * bt], hi = idx[2 * bt + 1];
        int u = hi + 1;
        int a = min(lo, u), e = max(lo, u);
        a = max(0, min(a, SS));
        e = max(0, min(e, SS));
        int cnt = e - a;
        float inv = 1.0f / (float)(cnt > 0 ? cnt : 1);
        size_t pb = (size_t)b * (SS + 1);
        float4 ve = P4[(pb + e) * 75 + j];
        float4 va = P4[(pb + a) * 75 + j];
        float4 o;
        o.x = (ve.x - va.x) * inv;
        o.y = (ve.y - va.y) * inv;
        o.z = (ve.z - va.z) * inv;
        o.w = (ve.w - va.w) * inv;
        out4[(size_t)bt * 75 + j] = o;
    }
}

extern "C" void kernel_launch(void* const* d_in, const int* in_sizes, int n_in,
                              void* d_out, int out_size, void* d_ws, size_t ws_size,
                              hipStream_t stream) {
    const int* x = (const int*)d_in[0];
    const int* idx = (const int*)d_in[1];
    const float* W = (const float*)d_in[2];
    float* out = (float*)d_out;

    char* ws = (char*)d_ws;
    int* leaves = (int*)ws;                    // B*SS ints   = 64 KiB
    float* csum = (float*)(ws + 65536);        // B*NC*DD f32 = 600 KiB
    float* P = (float*)(ws + 65536 + 614400);  // B*(SS+1)*DD = 18.8 MiB (16B-aligned)

    leaves_kernel<<<BB, 512, 0, stream>>>(x, idx, leaves);

    void* args[] = {(void*)&leaves, (void*)&W, (void*)&csum, (void*)&P};
    hipLaunchCooperativeKernel((void*)fusedP_kernel, dim3(BB * NC), dim3(NTB),
                               args, 0, stream);

    out_kernel<<<(BB * TT + 15) / 16, NTB, 0, stream>>>(idx, P, out);
}

// Round 7
// 115.988 us; speedup vs baseline: 1.7716x; 1.7716x over previous
//
#include <hip/hip_runtime.h>

// PhraseAveragePretrainedEmbedding — prefix-sum formulation, v6b.
// out[b,t,:] = (P[e]-P[a]) / max(e-a,1); spans contiguous by the XOR-mask
// identity (a=min(lo,hi+1), e=max(lo,hi+1)).
//
// v5 post-mortem: cg::grid.sync() cost ~65 µs on gfx950 — kernel boundaries
// are the cheapest global barrier. v6 = v4 structure + XCD batch swizzle
// (batch = blockIdx&7 so each XCD's 4 MB L2 holds its batch's 2.46 MB P
// slice) + nontemporal out stores (native ext_vector_type for the builtin)
// + hoisted-load leaves kernel.

#define BB 8
#define TT 4095
#define SS 2048
#define DD 300
#define PADIDX 1
#define CHUNK 32
#define NC (SS / CHUNK)  // 64
#define NTB 320

typedef float f4 __attribute__((ext_vector_type(4)));

__global__ __launch_bounds__(512) void leaves_kernel(const int* __restrict__ x,
                                                     const int* __restrict__ idx,
                                                     int* __restrict__ leaves) {
    int b = blockIdx.x, tid = threadIdx.x;
    int lane = tid & 63, w = tid >> 6;  // 8 waves
    __shared__ int wcnt[8];
    __shared__ int sbase;
    if (tid == 0) sbase = 0;
    const int* xb = x + b * TT;
    const int* ib = idx + b * 2 * TT;

    int xv[8];
    bool lf8[8];
#pragma unroll
    for (int k = 0; k < 8; ++k) {
        int t = tid + k * 512;
        xv[k] = 0;
        lf8[k] = false;
        if (t < TT) {
            xv[k] = xb[t];
            lf8[k] = (ib[2 * t] == ib[2 * t + 1]) && (xv[k] != PADIDX);
        }
    }
    __syncthreads();
#pragma unroll
    for (int k = 0; k < 8; ++k) {
        unsigned long long bal = __ballot(lf8[k]);
        if (lane == 0) wcnt[w] = __popcll(bal);
        __syncthreads();
        int off = sbase;
        for (int i = 0; i < w; ++i) off += wcnt[i];
        int pos = off + __popcll(bal & ((1ull << lane) - 1ull));
        if (lf8[k] && pos < SS) leaves[b * SS + pos] = xv[k];
        __syncthreads();
        if (tid == 0) {
            int s = 0;
            for (int i = 0; i < 8; ++i) s += wcnt[i];
            sbase += s;
        }
        __syncthreads();
    }
    for (int i = sbase + tid; i < SS; i += 512) leaves[b * SS + i] = PADIDX;
}

// 512 blocks: batch = blk & 7 (XCD swizzle), chunk = blk >> 3
__global__ __launch_bounds__(NTB) void csum_kernel(const int* __restrict__ leaves,
                                                   const float* __restrict__ W,
                                                   float* __restrict__ csum) {
    int blk = blockIdx.x;
    int b = blk & 7, c = blk >> 3;
    int tid = threadIdx.x;
    __shared__ int lf[CHUNK];
    if (tid < CHUNK) lf[tid] = leaves[b * SS + c * CHUNK + tid];
    __syncthreads();
    int d = tid;
    if (d >= DD) return;
    float acc = 0.f;
#pragma unroll 8
    for (int i = 0; i < CHUNK; ++i) acc += W[lf[i] * DD + d];
    csum[(b * NC + c) * DD + d] = acc;
}

__global__ __launch_bounds__(NTB) void buildP_kernel(const int* __restrict__ leaves,
                                                     const float* __restrict__ W,
                                                     const float* __restrict__ csum,
                                                     float* __restrict__ P) {
    int blk = blockIdx.x;
    int b = blk & 7, c = blk >> 3;
    int tid = threadIdx.x;
    __shared__ int lf[CHUNK];
    if (tid < CHUNK) lf[tid] = leaves[b * SS + c * CHUNK + tid];
    __syncthreads();
    int d = tid;
    if (d >= DD) return;

    float base = 0.f;
#pragma unroll 4
    for (int cc = 0; cc < c; ++cc) base += csum[(b * NC + cc) * DD + d];

    float v[CHUNK];
#pragma unroll
    for (int i = 0; i < CHUNK; ++i) v[i] = W[lf[i] * DD + d];

    float* Pb = P + (size_t)b * (SS + 1) * DD;
    int s0 = c * CHUNK;
    float run = base;
#pragma unroll
    for (int i = 0; i < CHUNK; ++i) {
        Pb[(s0 + i) * DD + d] = run;
        run += v[i];
    }
    if (c == NC - 1) Pb[SS * DD + d] = run;
}

// 2048 blocks: batch = blk & 7 (XCD swizzle), row-group = blk >> 3 (16 rows).
// 320 threads = 4 row-slots x 80 lanes (75 active float4 lanes per row).
__global__ __launch_bounds__(NTB) void out_kernel(const int* __restrict__ idx,
                                                  const float* __restrict__ P,
                                                  float* __restrict__ out) {
    int tid = threadIdx.x;
    int r = tid / 80, j = tid - r * 80;
    int b = blockIdx.x & 7;
    int g = blockIdx.x >> 3;
    const f4* P4 = (const f4*)(P + (size_t)b * (SS + 1) * DD);
    f4* out4 = (f4*)out;
    const int* ixb = idx + 2 * b * TT;
#pragma unroll
    for (int it = 0; it < 4; ++it) {
        int lr = g * 16 + r + it * 4;
        if (lr >= TT || j >= 75) continue;
        int lo = ixb[2 * lr], hi = ixb[2 * lr + 1];
        int u = hi + 1;
        int a = min(lo, u), e = max(lo, u);
        a = max(0, min(a, SS));
        e = max(0, min(e, SS));
        int cnt = e - a;
        float inv = 1.0f / (float)(cnt > 0 ? cnt : 1);
        f4 ve = P4[(size_t)e * 75 + j];
        f4 va = P4[(size_t)a * 75 + j];
        f4 o = (ve - va) * inv;
        __builtin_nontemporal_store(o, &out4[((size_t)b * TT + lr) * 75 + j]);
    }
}

extern "C" void kernel_launch(void* const* d_in, const int* in_sizes, int n_in,
                              void* d_out, int out_size, void* d_ws, size_t ws_size,
                              hipStream_t stream) {
    const int* x = (const int*)d_in[0];
    const int* idx = (const int*)d_in[1];
    const float* W = (const float*)d_in[2];
    float* out = (float*)d_out;

    char* ws = (char*)d_ws;
    int* leaves = (int*)ws;                    // B*SS ints   = 64 KiB
    float* csum = (float*)(ws + 65536);        // B*NC*DD f32 = 600 KiB
    float* P = (float*)(ws + 65536 + 614400);  // B*(SS+1)*DD = 18.8 MiB (16B-aligned)

    leaves_kernel<<<BB, 512, 0, stream>>>(x, idx, leaves);
    csum_kernel<<<BB * NC, NTB, 0, stream>>>(leaves, W, csum);
    buildP_kernel<<<BB * NC, NTB, 0, stream>>>(leaves, W, csum, P);
    out_kernel<<<(BB * TT + 15) / 16, NTB, 0, stream>>>(idx, P, out);
}

// Round 8
// 115.940 us; speedup vs baseline: 1.7724x; 1.0004x over previous
//
#include <hip/hip_runtime.h>

// PhraseAveragePretrainedEmbedding — prefix-sum formulation, v7.
// out[b,t,:] = (P[e]-P[a]) / max(e-a,1); spans contiguous by the XOR-mask
// identity (a=min(lo,hi+1), e=max(lo,hi+1)).
//
// v7: float4-ized gather/prefix pipeline (W rows = 1200 B = 75×f4, 16B
// aligned) — 4x fewer VMEM instructions in csum/buildP; int2 idx loads in
// leaves. Structure unchanged from v6b (4 plain kernels — kernel boundary
// is the cheapest device-wide barrier on gfx950; XCD batch swizzle so each
// XCD's 4 MB L2 holds its batch's 2.46 MB P slice; NT out stores).

#define BB 8
#define TT 4095
#define SS 2048
#define DD 300
#define D4 75            // DD/4
#define PADIDX 1
#define CHUNK 32
#define NC (SS / CHUNK)  // 64
#define NTB 320

typedef float f4 __attribute__((ext_vector_type(4)));

__global__ __launch_bounds__(512) void leaves_kernel(const int* __restrict__ x,
                                                     const int* __restrict__ idx,
                                                     int* __restrict__ leaves) {
    int b = blockIdx.x, tid = threadIdx.x;
    int lane = tid & 63, w = tid >> 6;  // 8 waves
    __shared__ int wcnt[8];
    __shared__ int sbase;
    if (tid == 0) sbase = 0;
    const int* xb = x + b * TT;
    const int2* ib2 = (const int2*)(idx + b * 2 * TT);

    int xv[8];
    bool lf8[8];
#pragma unroll
    for (int k = 0; k < 8; ++k) {
        int t = tid + k * 512;
        xv[k] = 0;
        lf8[k] = false;
        if (t < TT) {
            xv[k] = xb[t];
            int2 pr = ib2[t];
            lf8[k] = (pr.x == pr.y) && (xv[k] != PADIDX);
        }
    }
    __syncthreads();
#pragma unroll
    for (int k = 0; k < 8; ++k) {
        unsigned long long bal = __ballot(lf8[k]);
        if (lane == 0) wcnt[w] = __popcll(bal);
        __syncthreads();
        int off = sbase;
        for (int i = 0; i < w; ++i) off += wcnt[i];
        int pos = off + __popcll(bal & ((1ull << lane) - 1ull));
        if (lf8[k] && pos < SS) leaves[b * SS + pos] = xv[k];
        __syncthreads();
        if (tid == 0) {
            int s = 0;
            for (int i = 0; i < 8; ++i) s += wcnt[i];
            sbase += s;
        }
        __syncthreads();
    }
    for (int i = sbase + tid; i < SS; i += 512) leaves[b * SS + i] = PADIDX;
}

// 512 blocks: batch = blk & 7 (XCD swizzle), chunk = blk >> 3.
// 320 threads = 4 groups x 80 lanes (75 active f4 lanes). Group g sums its
// 8 rows with f4 loads; partials reduced via LDS.
__global__ __launch_bounds__(NTB) void csum_kernel(const int* __restrict__ leaves,
                                                   const float* __restrict__ W,
                                                   float* __restrict__ csum) {
    int blk = blockIdx.x;
    int b = blk & 7, c = blk >> 3;
    int tid = threadIdx.x;
    int g = tid / 80, j = tid - g * 80;
    __shared__ int lf[CHUNK];
    __shared__ f4 part[4][D4];
    if (tid < CHUNK) lf[tid] = leaves[b * SS + c * CHUNK + tid];
    __syncthreads();
    const f4* W4 = (const f4*)W;
    f4 acc = (f4)0.f;
    if (j < D4) {
#pragma unroll
        for (int i = 0; i < 8; ++i) acc += W4[(size_t)lf[g * 8 + i] * D4 + j];
        part[g][j] = acc;
    }
    __syncthreads();
    if (g == 0 && j < D4) {
        f4 s = part[0][j] + part[1][j] + part[2][j] + part[3][j];
        ((f4*)csum)[(b * NC + c) * D4 + j] = s;
    }
}

// Same grid mapping. f4 gather into LDS, f4 predecessor-csum base, f4 prefix
// accumulation in strict row order (k=0..31), group g writes rows 8g..8g+7.
__global__ __launch_bounds__(NTB) void buildP_kernel(const int* __restrict__ leaves,
                                                     const float* __restrict__ W,
                                                     const float* __restrict__ csum,
                                                     float* __restrict__ P) {
    int blk = blockIdx.x;
    int b = blk & 7, c = blk >> 3;
    int tid = threadIdx.x;
    int g = tid / 80, j = tid - g * 80;
    __shared__ int lf[CHUNK];
    __shared__ f4 sw[CHUNK][D4];  // 38400 B
    if (tid < CHUNK) lf[tid] = leaves[b * SS + c * CHUNK + tid];
    __syncthreads();
    const f4* W4 = (const f4*)W;
    if (j < D4) {
#pragma unroll
        for (int i = 0; i < 8; ++i)
            sw[g * 8 + i][j] = W4[(size_t)lf[g * 8 + i] * D4 + j];
    }
    __syncthreads();
    if (j >= D4) return;

    const f4* csum4 = (const f4*)csum;
    f4 base = (f4)0.f;
#pragma unroll 4
    for (int cc = 0; cc < c; ++cc) base += csum4[(b * NC + cc) * D4 + j];

    f4* P4 = (f4*)P + (size_t)b * (SS + 1) * D4;
    int s0 = c * CHUNK;
    f4 run = base;
    // catch up to this group's first row (row order preserved)
    for (int k = 0; k < g * 8; ++k) run += sw[k][j];
#pragma unroll
    for (int i = 0; i < 8; ++i) {
        int row = g * 8 + i;
        P4[(size_t)(s0 + row) * D4 + j] = run;
        run += sw[row][j];
    }
    if (c == NC - 1 && g == 3) P4[(size_t)SS * D4 + j] = run;
}

// 2048 blocks: batch = blk & 7 (XCD swizzle), row-group = blk >> 3 (16 rows).
// 320 threads = 4 row-slots x 80 lanes (75 active f4 lanes per row).
__global__ __launch_bounds__(NTB) void out_kernel(const int* __restrict__ idx,
                                                  const float* __restrict__ P,
                                                  float* __restrict__ out) {
    int tid = threadIdx.x;
    int r = tid / 80, j = tid - r * 80;
    int b = blockIdx.x & 7;
    int g = blockIdx.x >> 3;
    const f4* P4 = (const f4*)P + (size_t)b * (SS + 1) * D4;
    f4* out4 = (f4*)out;
    const int2* ixb = (const int2*)(idx + 2 * b * TT);
#pragma unroll
    for (int it = 0; it < 4; ++it) {
        int lr = g * 16 + r + it * 4;
        if (lr >= TT || j >= D4) continue;
        int2 pr = ixb[lr];
        int u = pr.y + 1;
        int a = min(pr.x, u), e = max(pr.x, u);
        a = max(0, min(a, SS));
        e = max(0, min(e, SS));
        int cnt = e - a;
        float inv = 1.0f / (float)(cnt > 0 ? cnt : 1);
        f4 ve = P4[(size_t)e * D4 + j];
        f4 va = P4[(size_t)a * D4 + j];
        f4 o = (ve - va) * inv;
        __builtin_nontemporal_store(o, &out4[((size_t)b * TT + lr) * D4 + j]);
    }
}

extern "C" void kernel_launch(void* const* d_in, const int* in_sizes, int n_in,
                              void* d_out, int out_size, void* d_ws, size_t ws_size,
                              hipStream_t stream) {
    const int* x = (const int*)d_in[0];
    const int* idx = (const int*)d_in[1];
    const float* W = (const float*)d_in[2];
    float* out = (float*)d_out;

    char* ws = (char*)d_ws;
    int* leaves = (int*)ws;                    // B*SS ints   = 64 KiB
    float* csum = (float*)(ws + 65536);        // B*NC*DD f32 = 600 KiB
    float* P = (float*)(ws + 65536 + 614400);  // B*(SS+1)*DD = 18.8 MiB (16B-aligned)

    leaves_kernel<<<BB, 512, 0, stream>>>(x, idx, leaves);
    csum_kernel<<<BB * NC, NTB, 0, stream>>>(leaves, W, csum);
    buildP_kernel<<<BB * NC, NTB, 0, stream>>>(leaves, W, csum, P);
    out_kernel<<<(BB * TT + 15) / 16, NTB, 0, stream>>>(idx, P, out);
}